// Round 10
// baseline (552.593 us; speedup 1.0000x reference)
//
#include <hip/hip_runtime.h>
#include <hip/hip_bf16.h>
#include <hip/hip_fp16.h>

// Self-attention, N=8192 tokens, H=1024, fp32 in/out.
//   1. x -> fp16; Wq/Wk/Wv -> fp16 transposed
//   2. q,k,v = x@W + b        (m97-structure 128x128 GEMM, batched)
//   3. S = q@k^T  fp16        (NEW round 20: 256x256 quad-buffered
//      counted-vmcnt MFMA GEMM — T2 swizzle + T4 counted waits + T5
//      setprio. m97 structure measured 773 TF @8k; this targets ~1300+.)
//   4. softmax: one wave per row, register-resident, ballot-prefix
//      compaction -> (idx<<16|half) pairs, zero-padded to x8.
//   5. out = P@v sparse gather, column-sliced (2 MB slice L2-resident
//      per XCD). Plateaued at ~184us after 5 attacks.
//
// Round-20 gemm256 design notes (race analysis in session log):
//   - BK=32, 4 LDS buffers (32 KB each: A 256x32 + B 256x32 fp16) = 128 KB.
//   - stagger 3: iter kt stages tile kt+3 into buf (kt+3)&3 = (kt-1)&3,
//     whose readers finished before THIS iter's barrier (stage is issued
//     after the barrier in program order).
//   - one raw s_barrier + one counted s_waitcnt vmcnt per iter. vmcnt(8)
//     works because loads retire in order: <=8 outstanding => the 4 oldest
//     (the tile about to be read) are complete. Tail: vmcnt(4) at kt=30,
//     vmcnt(0) at kt=31. NO __syncthreads in the loop (it would emit
//     vmcnt(0) and drain the pipeline).
//   - LDS swizzle: row stride is 64 B -> bank = f(row&1, slot16B) only;
//     slot' = slot ^ ((row>>1)&3) puts exactly 2 lanes per bank (free).
//     Staging pre-swizzles the GLOBAL source address (both-sides rule).
//   - epilogue: acc -> LDS (128x258 ushort) in two wm-halves -> whole-line
//     coalesced stores (no partial-line write-allocate).

typedef _Float16 f16x8 __attribute__((ext_vector_type(8)));
typedef float floatx4 __attribute__((ext_vector_type(4)));
typedef float floatx2 __attribute__((ext_vector_type(2)));
typedef unsigned short ushortx8 __attribute__((ext_vector_type(8)));

__device__ __forceinline__ unsigned short f2h(float f) {
  __half h = __float2half(f);
  return __builtin_bit_cast(unsigned short, h);
}
__device__ __forceinline__ float h2f(unsigned short u) {
  return __half2float(__builtin_bit_cast(__half, u));
}

// async global->LDS, 16B per lane. LDS dest is wave-uniform base; HW adds lane*16.
__device__ __forceinline__ void async16(const void* g, void* l) {
  __builtin_amdgcn_global_load_lds(
      (__attribute__((address_space(1))) unsigned int*)(g),
      (__attribute__((address_space(3))) unsigned int*)(l),
      16, 0, 0);
}

// ---------------- conversions / transposes ----------------

__global__ __launch_bounds__(256) void conv_f32_f16(const float* __restrict__ in,
                                                    unsigned short* __restrict__ out,
                                                    long n) {
  long i = ((long)blockIdx.x * 256 + threadIdx.x) * 4;
  if (i + 3 < n) {
    float4 f = *(const float4*)(in + i);
    ushort4 o;
    o.x = f2h(f.x); o.y = f2h(f.y); o.z = f2h(f.z); o.w = f2h(f.w);
    *(ushort4*)(out + i) = o;
  }
}

// in[rows][cols] fp32 -> out[cols][rows] fp16; z selects one of 3 matrices
__global__ __launch_bounds__(256) void transpose_f32_f16_3(const float* __restrict__ in0,
                                                           const float* __restrict__ in1,
                                                           const float* __restrict__ in2,
                                                           unsigned short* __restrict__ out,
                                                           int rows, int cols) {
  const float* in = (blockIdx.z == 0) ? in0 : (blockIdx.z == 1) ? in1 : in2;
  unsigned short* o = out + (size_t)blockIdx.z * rows * cols;
  __shared__ float tile[32][33];
  int bx = blockIdx.x * 32;
  int by = blockIdx.y * 32;
  int tx = threadIdx.x & 31, ty = threadIdx.x >> 5;
  #pragma unroll
  for (int yy = ty; yy < 32; yy += 8)
    tile[yy][tx] = in[(size_t)(by + yy) * cols + bx + tx];
  __syncthreads();
  #pragma unroll
  for (int yy = ty; yy < 32; yy += 8)
    o[(size_t)(bx + yy) * rows + by + tx] = f2h(tile[tx][yy]);
}

// ---- proj GEMM 128x128 (m97 recipe): C = A*B^T + bias, fp16, batched z ----
__global__ __launch_bounds__(256, 4)
void gemm_bt(const unsigned short* __restrict__ A,
             const unsigned short* __restrict__ B,
             int M, int Nn, int K,
             const float* __restrict__ b0, const float* __restrict__ b1,
             const float* __restrict__ b2,
             unsigned short* __restrict__ out) {
  B   += (size_t)blockIdx.z * Nn * K;
  out += (size_t)blockIdx.z * M * Nn;
  const float* bias = (blockIdx.z == 0) ? b0 : (blockIdx.z == 1) ? b1 : b2;
  __shared__ unsigned short smem[128 * 136];
  unsigned short* As = smem;
  unsigned short* Bs = smem + 128 * 32;
  const int tid  = threadIdx.x;
  const int wave = tid >> 6;
  const int lane = tid & 63;
  const int wm = wave >> 1, wn = wave & 1;
  const int quad = lane >> 4, l16 = lane & 15;
  const long bm = (long)blockIdx.y * 128;
  const long bn = (long)blockIdx.x * 128;

  floatx4 acc[4][4] = {};

  const int srow = wave * 32 + (lane >> 2);
  const int scol = (lane & 3) * 8;
  const unsigned short* gA0 = A + (bm + srow) * (long)K + scol;
  const unsigned short* gA1 = gA0 + 16L * K;
  const unsigned short* gB0 = B + (bn + srow) * (long)K + scol;
  const unsigned short* gB1 = gB0 + 16L * K;
  unsigned short* lA0 = &As[(wave * 32) * 32];
  unsigned short* lA1 = &As[(wave * 32 + 16) * 32];
  unsigned short* lB0 = &Bs[(wave * 32) * 32];
  unsigned short* lB1 = &Bs[(wave * 32 + 16) * 32];

  for (int kk = 0; kk < K; kk += 32) {
    async16(gA0 + kk, lA0);
    async16(gA1 + kk, lA1);
    async16(gB0 + kk, lB0);
    async16(gB1 + kk, lB1);
    __syncthreads();
    f16x8 af[4], bfv[4];
    #pragma unroll
    for (int i = 0; i < 4; ++i) {
      af[i]  = *reinterpret_cast<const f16x8*>(&As[(wm * 64 + i * 16 + l16) * 32 + quad * 8]);
      bfv[i] = *reinterpret_cast<const f16x8*>(&Bs[(wn * 64 + i * 16 + l16) * 32 + quad * 8]);
    }
    #pragma unroll
    for (int i = 0; i < 4; ++i)
      #pragma unroll
      for (int j = 0; j < 4; ++j)
        acc[i][j] = __builtin_amdgcn_mfma_f32_16x16x32_f16(af[i], bfv[j], acc[i][j], 0, 0, 0);
    __syncthreads();
  }
  // epilogue via LDS (whole-line stores)
  #pragma unroll
  for (int i = 0; i < 4; ++i) {
    const int row0 = wm * 64 + i * 16 + quad * 4;
    #pragma unroll
    for (int j = 0; j < 4; ++j) {
      const int col = wn * 64 + j * 16 + l16;
      const float cb = bias[bn + col];
      #pragma unroll
      for (int r = 0; r < 4; ++r)
        smem[(row0 + r) * 136 + col] = f2h(acc[i][j][r] + cb);
    }
  }
  __syncthreads();
  #pragma unroll
  for (int u = 0; u < 8; ++u) {
    const int chunk = u * 256 + tid;
    const int row = chunk >> 4;
    const int cc = chunk & 15;
    const ushortx8 val = *reinterpret_cast<const ushortx8*>(&smem[row * 136 + cc * 8]);
    *reinterpret_cast<ushortx8*>(&out[(bm + row) * (long)Nn + bn + cc * 8]) = val;
  }
}

// ---- scores GEMM 256x256, quad-buffered counted-vmcnt (round 20) ----
// C[8192][8192] = A[8192][1024] * B[8192][1024]^T, fp16 in/out, f32 acc.
// 512 threads = 8 waves (2M x 4N); per-wave output 128x64.
__global__ __launch_bounds__(512, 2)
void gemm256(const unsigned short* __restrict__ A,
             const unsigned short* __restrict__ B,
             unsigned short* __restrict__ out) {
  constexpr int Nd = 8192;
  constexpr int K = 1024;
  __shared__ unsigned short smem[65536];  // 128 KB: 4 bufs x (A 8192 + B 8192)
  const int tid  = threadIdx.x;
  const int lane = tid & 63;
  const int wave = tid >> 6;
  const int wm = wave >> 2, wn = wave & 3;
  const int quad = lane >> 4, l16 = lane & 15;

  // XCD-aware bijective swizzle (1024 blocks % 8 == 0)
  const unsigned lin = blockIdx.y * gridDim.x + blockIdx.x;
  const unsigned nb  = gridDim.x * gridDim.y;          // 1024
  const unsigned swz = (lin & 7u) * (nb >> 3) + (lin >> 3);
  const long bm = (long)(swz >> 5) * 256;              // gridDim.x == 32
  const long bn = (long)(swz & 31u) * 256;

  floatx4 acc[8][4] = {};

  // staging: tile kt -> buf kt&3. chunk c in [0,1024): row=c>>2, phys
  // slot=c&3, logical slot = (c&3)^((row>>1)&3); thread t covers c=t,t+512.
  const int c0 = tid, c1 = tid + 512;
  const int r0 = c0 >> 2, r1 = c1 >> 2;
  const int sl0 = (c0 & 3) ^ ((r0 >> 1) & 3);
  const int sl1 = (c1 & 3) ^ ((r1 >> 1) & 3);
  const unsigned short* gA0 = A + (bm + r0) * (long)K + sl0 * 8;
  const unsigned short* gA1 = A + (bm + r1) * (long)K + sl1 * 8;
  const unsigned short* gB0 = B + (bn + r0) * (long)K + sl0 * 8;
  const unsigned short* gB1 = B + (bn + r1) * (long)K + sl1 * 8;
  const int ldsw0 = (c0 & ~63) * 8;   // wave-uniform ushort offset
  const int ldsw1 = (c1 & ~63) * 8;

  auto STAGE = [&](int kt) {
    unsigned short* bufA = smem + (kt & 3) * 16384;
    unsigned short* bufB = bufA + 8192;
    const int ko = kt * 32;
    async16(gA0 + ko, bufA + ldsw0);
    async16(gA1 + ko, bufA + ldsw1);
    async16(gB0 + ko, bufB + ldsw0);
    async16(gB1 + ko, bufB + ldsw1);
  };

  STAGE(0); STAGE(1); STAGE(2);

  for (int kt = 0; kt < 32; ++kt) {
    const unsigned short* bufA = smem + (kt & 3) * 16384;
    const unsigned short* bufB = bufA + 8192;
    // counted wait: tile kt's 4 loads are the oldest; <=N outstanding
    // (in-order retirement) => tile kt landed. Never drains the pipeline.
    if (kt <= 29)      asm volatile("s_waitcnt vmcnt(8)" ::: "memory");
    else if (kt == 30) asm volatile("s_waitcnt vmcnt(4)" ::: "memory");
    else               asm volatile("s_waitcnt vmcnt(0)" ::: "memory");
    __builtin_amdgcn_s_barrier();
    __builtin_amdgcn_sched_barrier(0);
    if (kt + 3 < 32) STAGE(kt + 3);  // targets buf (kt-1)&3: readers done

    // B fragments for this K-tile (shared across all 4 A-quadrants)
    f16x8 bf[4];
    #pragma unroll
    for (int j = 0; j < 4; ++j) {
      const int R = wn * 64 + j * 16 + l16;
      bf[j] = *reinterpret_cast<const f16x8*>(
          bufB + R * 32 + ((quad ^ ((R >> 1) & 3)) * 8));
    }
    #pragma unroll
    for (int qd = 0; qd < 4; ++qd) {
      const int R0 = wm * 128 + (2 * qd) * 16 + l16;
      const int R1 = R0 + 16;
      const f16x8 a0 = *reinterpret_cast<const f16x8*>(
          bufA + R0 * 32 + ((quad ^ ((R0 >> 1) & 3)) * 8));
      const f16x8 a1 = *reinterpret_cast<const f16x8*>(
          bufA + R1 * 32 + ((quad ^ ((R1 >> 1) & 3)) * 8));
      __builtin_amdgcn_s_setprio(1);
      #pragma unroll
      for (int j = 0; j < 4; ++j) {
        acc[2 * qd][j] =
            __builtin_amdgcn_mfma_f32_16x16x32_f16(a0, bf[j], acc[2 * qd][j], 0, 0, 0);
        acc[2 * qd + 1][j] =
            __builtin_amdgcn_mfma_f32_16x16x32_f16(a1, bf[j], acc[2 * qd + 1][j], 0, 0, 0);
      }
      __builtin_amdgcn_s_setprio(0);
    }
  }

  // epilogue: two wm-halves through LDS (128 x 258 ushorts), whole-line stores
  __syncthreads();
  #pragma unroll
  for (int half = 0; half < 2; ++half) {
    if (wm == half) {
      #pragma unroll
      for (int i = 0; i < 8; ++i)
        #pragma unroll
        for (int j = 0; j < 4; ++j)
          #pragma unroll
          for (int r = 0; r < 4; ++r)
            smem[(i * 16 + quad * 4 + r) * 258 + wn * 64 + j * 16 + l16] =
                f2h(acc[i][j][r]);
    }
    __syncthreads();
    #pragma unroll
    for (int s = 0; s < 8; ++s) {
      const int chunk = s * 512 + tid;          // 4096 chunks of 16B
      const int row = chunk >> 5, cc = chunk & 31;
      *reinterpret_cast<ushortx8*>(
          out + (bm + half * 128 + row) * (long)Nd + bn + cc * 8) =
          *reinterpret_cast<const ushortx8*>(smem + row * 258 + cc * 8);
    }
    __syncthreads();
  }
}

// ---- softmax + compaction: ONE WAVE PER ROW ----
// Stripe = 64 lanes x 8 elems = 512 ushorts; 16 stripes cover the row.
// elem idx = u*512 + lane*8 + e. Exact row max, f32 exp, single f2h
// rounding. Nonzeros packed as (idx<<16|halfbits) pairs via ballot
// prefix-sum, zero-padded to x8. nnz[row] = padded count.
__global__ __launch_bounds__(256) void softmax_compact(unsigned short* __restrict__ S,
                                                       int* __restrict__ nnz, int n) {
  const int wid  = threadIdx.x >> 6;
  const int lane = threadIdx.x & 63;
  const int row  = blockIdx.x * 4 + wid;
  unsigned short* prow = S + ((size_t)row << 13);  // n = 8192

  ushortx8 c[16];
  #pragma unroll
  for (int u = 0; u < 16; ++u)
    c[u] = *reinterpret_cast<const ushortx8*>(&prow[u * 512 + lane * 8]);

  float m0 = -1e30f, m1 = -1e30f, m2 = -1e30f, m3 = -1e30f;
  #pragma unroll
  for (int u = 0; u < 16; ++u) {
    m0 = fmaxf(m0, fmaxf(h2f(c[u][0]), h2f(c[u][4])));
    m1 = fmaxf(m1, fmaxf(h2f(c[u][1]), h2f(c[u][5])));
    m2 = fmaxf(m2, fmaxf(h2f(c[u][2]), h2f(c[u][6])));
    m3 = fmaxf(m3, fmaxf(h2f(c[u][3]), h2f(c[u][7])));
  }
  float m = fmaxf(fmaxf(m0, m1), fmaxf(m2, m3));
  #pragma unroll
  for (int off = 32; off > 0; off >>= 1)
    m = fmaxf(m, __shfl_xor(m, off, 64));

  float s0 = 0.f, s1 = 0.f, s2 = 0.f, s3 = 0.f;
  #pragma unroll
  for (int u = 0; u < 16; ++u) {
    s0 += __expf(h2f(c[u][0]) - m) + __expf(h2f(c[u][4]) - m);
    s1 += __expf(h2f(c[u][1]) - m) + __expf(h2f(c[u][5]) - m);
    s2 += __expf(h2f(c[u][2]) - m) + __expf(h2f(c[u][6]) - m);
    s3 += __expf(h2f(c[u][3]) - m) + __expf(h2f(c[u][7]) - m);
  }
  float s = (s0 + s1) + (s2 + s3);
  #pragma unroll
  for (int off = 32; off > 0; off >>= 1)
    s += __shfl_xor(s, off, 64);
  const float inv = 1.0f / s;

  unsigned int* pairs = (unsigned int*)prow;
  const int cap = 4096 - 8;
  int base = 0;
  #pragma unroll
  for (int u = 0; u < 16; ++u) {
    #pragma unroll
    for (int e = 0; e < 8; ++e) {
      const unsigned short hh = f2h(__expf(h2f(c[u][e]) - m) * inv);
      const unsigned long long mask = __ballot(hh != 0);
      if (hh) {
        const int pos = base + (int)__popcll(mask & ((1ull << lane) - 1ull));
        if (pos < cap)
          pairs[pos] = ((unsigned)(u * 512 + lane * 8 + e) << 16) | hh;
      }
      base += (int)__popcll(mask);
    }
  }
  const int c_cl = base < cap ? base : cap;
  const int padded = (c_cl + 7) & ~7;
  if (lane < padded - c_cl) pairs[c_cl + lane] = 0u;
  if (lane == 0) nnz[row] = padded;
}

// ---- sparse PV, column-sliced (unchanged; 183-185us plateau) ----
__global__ __launch_bounds__(256) void pv_sliced(const unsigned short* __restrict__ S,
                                                 const int* __restrict__ nnz,
                                                 const unsigned short* __restrict__ v,
                                                 float* __restrict__ out,
                                                 int n) {
  const int wave = threadIdx.x >> 6;
  const int lane = threadIdx.x & 63;
  const int colbase = blockIdx.x * 128 + lane * 2;
  const unsigned colbyte = (unsigned)colbase * 2;
  const char* __restrict__ vb = (const char*)v;
  const char* __restrict__ sb = (const char*)S;

  #pragma unroll 1
  for (int r = 0; r < 4; ++r) {
    const int row = blockIdx.y + ((wave << 2) + r) * 512;
    int craw = nnz[row];
    craw = craw < 0 ? 0 : (craw > 4096 ? 4096 : craw);
    const int cnt = __builtin_amdgcn_readfirstlane(craw);
    const unsigned rowbase = (unsigned)row << 14;
    const unsigned pend = rowbase + 16384 - 32;
    unsigned poff = rowbase;
    uint4 q0 = *(const uint4*)(sb + poff);
    uint4 q1 = *(const uint4*)(sb + poff + 16);
    float a0 = 0.f, a1 = 0.f;
    for (int j = 0; j < cnt; j += 8) {
      const unsigned pn = (poff + 32 <= pend) ? poff + 32 : pend;
      const uint4 n0 = *(const uint4*)(sb + pn);
      const uint4 n1 = *(const uint4*)(sb + pn + 16);
      const unsigned p[8] = {q0.x, q0.y, q0.z, q0.w, q1.x, q1.y, q1.z, q1.w};
      #pragma unroll
      for (int u = 0; u < 8; ++u) {
        const ushort2 vv = *(const ushort2*)(vb + (((p[u] & 0xffff0000u) >> 5) + colbyte));
        const float w = h2f((unsigned short)(p[u] & 0xffffu));
        a0 += w * h2f(vv.x);
        a1 += w * h2f(vv.y);
      }
      q0 = n0; q1 = n1; poff = pn;
    }
    floatx2 o = {a0, a1};
    __builtin_nontemporal_store(o, (floatx2*)(out + ((size_t)row << 10) + colbase));
  }
}

// ---------------- launch ----------------
extern "C" void kernel_launch(void* const* d_in, const int* in_sizes, int n_in,
                              void* d_out, int out_size, void* d_ws, size_t ws_size,
                              hipStream_t stream) {
  const int N = 8192, H = 1024;
  const float* x  = (const float*)d_in[0];
  const float* Wq = (const float*)d_in[1];
  const float* bq = (const float*)d_in[2];
  const float* Wk = (const float*)d_in[3];
  const float* bk = (const float*)d_in[4];
  const float* Wv = (const float*)d_in[5];
  const float* bv = (const float*)d_in[6];

  char* p = (char*)d_ws;
  unsigned short* xh  = (unsigned short*)p; p += (size_t)N * H * 2;      // 16 MB
  unsigned short* WT  = (unsigned short*)p; p += (size_t)3 * H * H * 2;  // 6 MB
  unsigned short* qkv = (unsigned short*)p; p += (size_t)3 * N * H * 2;  // 48 MB
  unsigned short* S   = (unsigned short*)p; p += (size_t)N * N * 2;      // 128 MB
  int*            nnz = (int*)p;            p += (size_t)N * 4;          // 32 KB
  if ((size_t)(p - (char*)d_ws) > ws_size) return;
  unsigned short* qh = qkv;
  unsigned short* kh = qkv + (size_t)N * H;
  unsigned short* vh = qkv + (size_t)2 * N * H;

  conv_f32_f16<<<(N * H / 4 + 255) / 256, 256, 0, stream>>>(x, xh, (long)N * H);
  transpose_f32_f16_3<<<dim3(H / 32, H / 32, 3), 256, 0, stream>>>(Wq, Wk, Wv, WT, H, H);

  // batched projections: qkv[z][N][H] fp16 (m97 structure)
  gemm_bt<<<dim3(H / 128, N / 128, 3), 256, 0, stream>>>(xh, WT, N, H, H,
                                                         bq, bk, bv, qkv);

  // scores: S[N][N] fp16, 256^2 quad-buffered pipeline
  gemm256<<<dim3(N / 256, N / 256), 512, 0, stream>>>(qh, kh, S);

  // softmax + in-place compaction: one wave per row
  softmax_compact<<<N / 4, 256, 0, stream>>>(S, nnz, N);
  // sparse PV gather, column-sliced for per-XCD L2 residency
  pv_sliced<<<dim3(8, N / 16), 256, 0, stream>>>(S, nnz, vh, (float*)d_out, N);
}